// Round 1
// baseline (611.751 us; speedup 1.0000x reference)
//
#include <hip/hip_runtime.h>
#include <math.h>

#define E 100
#define V 3
#define S 100
#define T 10
#define NB 8192
#define SCALE 0.1f
#define PADV  (-4294967295.0f)
#define XP 102            // xs LDS pitch (float2-aligned, breaks worst bank conflicts)

// ws float offsets (prep outputs) — total 716 floats
#define WS_H  0     // [3][100]  H = SCALE * (of2 @ W1)
#define WS_G  304   // [3][100]  G = SCALE * (of3 @ W4)
#define WS_B1 608   // [100]     fc1_b passthrough
#define WS_C1 708   // [3]       SCALE * of2·b1
#define WS_C2 712   // [3]       SCALE * of3·b4

// Algebra: of1/of4 are never materialized.
//   m1[s,v]  = x[s,:]·H[v,:] + c1[v]          (masked -> PADV, softmax over s)
//   y[v,k]   = sum_s sm1[s,v] * x[s,k]
//   ws1[v,e] = y[v,:]·W1[e,:] + b1[e]          (since sum_s sm1 == 1 exactly)
//   m2[t,v]  = tag[t,:]·G[v,:] + c2[v]         (softmax over t)
//   out[t]   = sum_v sm2[t,v] * (ws1[v,:]·tag[t,:])

__global__ __launch_bounds__(256) void prep_kernel(const float* __restrict__ vk,
        const float* __restrict__ fc1w, const float* __restrict__ fc1b,
        const float* __restrict__ fc2w, const float* __restrict__ fc2b,
        const float* __restrict__ fc3w, const float* __restrict__ fc3b,
        const float* __restrict__ fc4w, const float* __restrict__ fc4b,
        float* __restrict__ ws)
{
    __shared__ __align__(16) float wsm[E * E];   // W1 (blk 0) or W4 (blk 1)
    __shared__ __align__(16) float ofs[V * E];   // of2 (blk 0) or of3 (blk 1)
    const int t   = threadIdx.x;
    const int blk = blockIdx.x;                  // 0: H/c1/b1 path, 1: G/c2 path
    const float* WA = blk ? fc4w : fc1w;
    const float* WB = blk ? fc3w : fc2w;
    const float* bB = blk ? fc3b : fc2b;
    const float* bA = blk ? fc4b : fc1b;

    for (int i = t; i < E * E / 4; i += 256)      // stage WA into LDS
        *(float4*)(&wsm[4 * i]) = *(const float4*)(WA + 4 * i);

    for (int o = t; o < V * E; o += 256) {        // of[v][e] = vk[v,:]·WB[e,:] + bB[e]
        int v = o / E, e = o % E;
        const float* vr = vk + v * E;
        const float* wr = WB + e * E;
        float acc = bB[e];
        for (int k = 0; k < E; k += 4) {
            float4 a = *(const float4*)(vr + k);
            float4 w = *(const float4*)(wr + k);
            acc += a.x * w.x + a.y * w.y + a.z * w.z + a.w * w.w;
        }
        ofs[o] = acc;
    }
    __syncthreads();

    for (int o = t; o < V * E; o += 256) {        // H/G[v][k] = SCALE * sum_e of[v][e]*WA[e][k]
        int v = o / E, k = o % E;
        float acc = 0.f;
        for (int e = 0; e < E; ++e) acc += ofs[v * E + e] * wsm[e * E + k];
        ws[(blk ? WS_G : WS_H) + o] = acc * SCALE;
    }
    if (t < V) {                                   // c[v] = SCALE * sum_e bA[e]*of[v][e]
        float acc = 0.f;
        for (int e = 0; e < E; ++e) acc += bA[e] * ofs[t * E + e];
        ws[(blk ? WS_C2 : WS_C1) + t] = acc * SCALE;
    }
    if (blk == 0 && t < E) ws[WS_B1 + t] = fc1b[t];
}

__global__ __launch_bounds__(256) void mvke_main(const float* __restrict__ x,
        const float* __restrict__ tag, const float* __restrict__ fc1w,
        const float* __restrict__ ws, float* __restrict__ out)
{
    __shared__ __align__(16) float xs[S * XP];     // 10200 f
    __shared__ __align__(16) float tg[T * E];      // 1000 f
    __shared__ __align__(16) float Hs[V * E];      // 300 f
    __shared__ __align__(16) float Gs[V * E];      // 300 f
    __shared__ __align__(16) float b1s[E];         // 100 f
    __shared__ float cs[8];                         // c1 in [0..2], c2 in [4..6]
    __shared__ __align__(16) float m1s[V * S];     // [v][s]
    __shared__ __align__(16) float sm1s[V * S];    // [v][s]
    __shared__ __align__(16) float ys[V * E];      // [v][k]
    __shared__ __align__(16) float ws1s[V * E];    // [v][e]
    __shared__ float m2s[T * V];                    // [t*3+v]
    __shared__ float sm2s[T * V];
    __shared__ float p3[32];
    // total ~13.2K floats = 52.8 KB -> 3 blocks/CU

    const int t = threadIdx.x;
    const int b = blockIdx.x;
    const float* xb = x   + (size_t)b * (S * E);
    const float* tb = tag + (size_t)b * (T * E);

    // ---- stage x, tag (coalesced float4) ----
    for (int i = t; i < (S * E + T * E) / 4; i += 256) {   // 2750
        if (i < S * E / 4) {
            int s = i / 25, kk = (i % 25) * 4;
            float4 v = *(const float4*)(xb + s * E + kk);
            float* d = &xs[s * XP + kk];
            *(float2*)(d)     = make_float2(v.x, v.y);
            *(float2*)(d + 2) = make_float2(v.z, v.w);
        } else {
            int j = i - S * E / 4;                          // < 250
            *(float4*)(&tg[4 * j]) = *(const float4*)(tb + 4 * j);
        }
    }
    // ---- stage small precomputed arrays ----
    if (t < 75)        *(float4*)(&Hs[4 * t])         = *(const float4*)(ws + WS_H  + 4 * t);
    else if (t < 150)  *(float4*)(&Gs[4 * (t - 75)])  = *(const float4*)(ws + WS_G  + 4 * (t - 75));
    else if (t < 175)  *(float4*)(&b1s[4 * (t - 150)]) = *(const float4*)(ws + WS_B1 + 4 * (t - 150));
    else if (t < 183)  cs[t - 175] = ws[WS_C1 + (t - 175)];
    __syncthreads();

    // ---- phase 1: m1 rows (t<100) + mask ; m2 on otherwise-idle wave 2 ----
    if (t < S) {
        const float* xr = &xs[t * XP];
        float a0 = cs[0], a1 = cs[1], a2 = cs[2], ra = 0.f;
        #pragma unroll 2
        for (int k = 0; k < E; k += 2) {
            float2 xv = *(const float2*)(xr + k);
            float2 h0 = *(const float2*)(&Hs[k]);
            float2 h1 = *(const float2*)(&Hs[E + k]);
            float2 h2 = *(const float2*)(&Hs[2 * E + k]);
            a0 += xv.x * h0.x + xv.y * h0.y;
            a1 += xv.x * h1.x + xv.y * h1.y;
            a2 += xv.x * h2.x + xv.y * h2.y;
            ra += fabsf(xv.x) + fabsf(xv.y);
        }
        bool z = (ra == 0.f);
        m1s[t]         = z ? PADV : a0;
        m1s[S + t]     = z ? PADV : a1;
        m1s[2 * S + t] = z ? PADV : a2;
    } else if (t >= 128 && t < 128 + T * V) {
        int o = t - 128, tt = o / V, v = o % V;
        const float* tr = &tg[tt * E];
        const float* gr = &Gs[v * E];
        float acc = cs[4 + v];
        #pragma unroll 2
        for (int k = 0; k < E; k += 4) {
            float4 a = *(const float4*)(tr + k);
            float4 g = *(const float4*)(gr + k);
            acc += a.x * g.x + a.y * g.y + a.z * g.z + a.w * g.w;
        }
        m2s[o] = acc;
    }
    __syncthreads();

    // ---- softmax over S per v (waves 0-2) ; softmax over T per v (wave 3) ----
    {
        int wv = t >> 6, lane = t & 63;
        if (wv < V) {
            float x1 = m1s[wv * S + lane];
            float x2 = (lane + 64 < S) ? m1s[wv * S + lane + 64] : -INFINITY;
            float mx = fmaxf(x1, x2);
            for (int d = 32; d > 0; d >>= 1) mx = fmaxf(mx, __shfl_xor(mx, d));
            float e1 = __expf(x1 - mx);
            float e2 = (lane + 64 < S) ? __expf(x2 - mx) : 0.f;
            float sm = e1 + e2;
            for (int d = 32; d > 0; d >>= 1) sm += __shfl_xor(sm, d);
            float inv = 1.f / sm;
            sm1s[wv * S + lane] = e1 * inv;
            if (lane + 64 < S) sm1s[wv * S + lane + 64] = e2 * inv;
        } else if (lane < V) {
            float mm[T];
            float mx = -INFINITY;
            for (int tt = 0; tt < T; ++tt) { mm[tt] = m2s[tt * V + lane]; mx = fmaxf(mx, mm[tt]); }
            float ee[T];
            float sum = 0.f;
            for (int tt = 0; tt < T; ++tt) { ee[tt] = __expf(mm[tt] - mx); sum += ee[tt]; }
            float inv = 1.f / sum;
            for (int tt = 0; tt < T; ++tt) sm2s[tt * V + lane] = ee[tt] * inv;
        }
    }
    __syncthreads();

    // ---- y[v][k] = sum_s sm1[v][s] * xs[s][k]   (300 outputs, conflict-free columns) ----
    for (int o = t; o < V * E; o += 256) {
        int v = o / E, k = o % E;
        const float* smr = &sm1s[v * S];
        const float* xc  = &xs[k];
        float acc = 0.f;
        #pragma unroll 4
        for (int s = 0; s < S; ++s) acc += smr[s] * xc[s * XP];
        ys[o] = acc;
    }
    __syncthreads();

    // ---- ws1[v][e] = b1[e] + y[v,:]·W1[e,:]   (W1 rows contiguous, from global) ----
    for (int o = t; o < V * E; o += 256) {
        int v = o / E, e = o % E;
        const float* wr = fc1w + e * E;
        const float* yr = &ys[v * E];
        float acc = b1s[e];
        #pragma unroll 5
        for (int k = 0; k < E; k += 4) {
            float4 w  = *(const float4*)(wr + k);
            float4 yv = *(const float4*)(&yr[k]);
            acc += w.x * yv.x + w.y * yv.y + w.z * yv.z + w.w * yv.w;
        }
        ws1s[o] = acc;
    }
    __syncthreads();

    // ---- p3[t*3+v] = sm2[t][v] * (ws1[v,:]·tag[t,:]) ----
    if (t < T * V) {
        int tt = t / V, v = t % V;
        const float* wr = &ws1s[v * E];
        const float* tr = &tg[tt * E];
        float acc = 0.f;
        #pragma unroll 5
        for (int k = 0; k < E; k += 4) {
            float4 w = *(const float4*)(wr + k);
            float4 a = *(const float4*)(tr + k);
            acc += w.x * a.x + w.y * a.y + w.z * a.z + w.w * a.w;
        }
        p3[t] = sm2s[t] * acc;
    }
    __syncthreads();
    if (t < T)
        out[(size_t)b * T + t] = p3[t * V] + p3[t * V + 1] + p3[t * V + 2];
}

extern "C" void kernel_launch(void* const* d_in, const int* in_sizes, int n_in,
                              void* d_out, int out_size, void* d_ws, size_t ws_size,
                              hipStream_t stream) {
    const float* x    = (const float*)d_in[0];
    const float* tag  = (const float*)d_in[1];
    const float* vk   = (const float*)d_in[2];
    const float* fc1w = (const float*)d_in[3];
    const float* fc1b = (const float*)d_in[4];
    const float* fc2w = (const float*)d_in[5];
    const float* fc2b = (const float*)d_in[6];
    const float* fc3w = (const float*)d_in[7];
    const float* fc3b = (const float*)d_in[8];
    const float* fc4w = (const float*)d_in[9];
    const float* fc4b = (const float*)d_in[10];
    float* out = (float*)d_out;
    float* ws  = (float*)d_ws;

    hipLaunchKernelGGL(prep_kernel, dim3(2), dim3(256), 0, stream,
                       vk, fc1w, fc1b, fc2w, fc2b, fc3w, fc3b, fc4w, fc4b, ws);
    hipLaunchKernelGGL(mvke_main, dim3(NB), dim3(256), 0, stream,
                       x, tag, fc1w, ws, out);
}